// Round 11
// baseline (290.285 us; speedup 1.0000x reference)
//
#include <hip/hip_runtime.h>
#include <hip/hip_bf16.h>

#define NN 20000
#define MM 32
#define EE 20
#define HH 128
#define GRID 2048
#define LOG2E 1.44269504088896f
#define LN2   0.69314718055995f

typedef __attribute__((ext_vector_type(8))) short bf16x8;
typedef __attribute__((ext_vector_type(4))) float f32x4;

// ---------- helpers ----------
__device__ __forceinline__ float bf_lo(unsigned int u) {
    return __uint_as_float(u << 16);
}
__device__ __forceinline__ float bf_hi(unsigned int u) {
    return __uint_as_float(u & 0xFFFF0000u);
}
__device__ __forceinline__ unsigned int pack_bf2(float lo, float hi) {
    unsigned int a = __float_as_uint(lo);
    unsigned int b = __float_as_uint(hi);
    a += 0x7FFFu + ((a >> 16) & 1u);
    b += 0x7FFFu + ((b >> 16) & 1u);
    return (a >> 16) | (b & 0xFFFF0000u);
}
__device__ __forceinline__ unsigned short bf16r(float v) {
    unsigned int u = __float_as_uint(v);
    u += 0x7FFFu + ((u >> 16) & 1u);
    return (unsigned short)(u >> 16);
}
__device__ __forceinline__ float softplusf(float x) {
    return fmaxf(x, 0.f) + __logf(1.f + __expf(-fabsf(x)));
}

// ---------- kernel 1: build Pfrag — MFMA B fragments of proj weights (bf16) ----------
// Pfrag flat index: ((tile*4+ks)*64 + l)*8 + i   (131072 bf16, 256 KB)
// tile<32: filt; tile>=32: core. Pre-scaled by LOG2E.
__global__ void build_pfrag(const float* __restrict__ cheW,
                            const float* __restrict__ vdwW,
                            unsigned short* __restrict__ Pfrag) {
    int t = blockIdx.x * 256 + threadIdx.x;   // < 131072
    int i = t & 7;
    int l = (t >> 3) & 63;
    int ks = (t >> 9) & 3;
    int tile = t >> 11;                       // 0..63
    int j = (tile & 31) * 16 + (l & 15);      // pair col < 512
    int slot = tile >> 5;
    int b = j >> 8, sec = (j >> 7) & 1, h = j & 127;
    int klocal = (l >> 4) * 8 + i;
    int row = (sec ? 256 : 0) + ks * 32 + klocal;
    const float* W = b ? vdwW : cheW;
    Pfrag[t] = bf16r(LOG2E * W[row * 256 + slot * 128 + h]);
}

// ---------- kernel 2: build Bfrag (edge-weight MFMA B fragments) + biasP ----------
// Both pre-scaled by LOG2E.
__global__ void build_bfrag(const float* __restrict__ cheWf, const float* __restrict__ cheBf,
                            const float* __restrict__ cheW,  const float* __restrict__ cheBfull,
                            const float* __restrict__ vdwWf, const float* __restrict__ vdwBf,
                            const float* __restrict__ vdwW,  const float* __restrict__ vdwBfull,
                            unsigned short* __restrict__ Bfrag, float* __restrict__ biasP) {
    int t = blockIdx.x * 256 + threadIdx.x;   // < 2048
    int b = t >> 10, w = (t >> 9) & 1, tc = (t >> 6) & 7, l = t & 63;
    int lhi = l >> 4, llo = l & 15;
    int h = w * 64 + (tc >> 1) * 16 + llo;    // < 128
    int slot = tc & 1;
    int jcol = slot * 128 + h;                // < 256
    const float* Wf = b ? vdwWf : cheWf;
    const float* W  = b ? vdwW  : cheW;

    unsigned short o[8];
#pragma unroll
    for (int i = 0; i < 8; ++i) {
        int k = lhi * 8 + i;
        float a = 0.f;
        if (k < EE)
            for (int h2 = 0; h2 < 128; ++h2)
                a = fmaf(Wf[k * 128 + h2], W[(128 + h2) * 256 + jcol], a);
        o[i] = bf16r(LOG2E * a);
    }
#pragma unroll
    for (int i = 0; i < 8; ++i) Bfrag[t * 8 + i] = o[i];

    if (t < 512) {
        int bb = t >> 8, sl = (t >> 7) & 1, hh = t & 127;
        int jc = sl * 128 + hh;
        const float* bfv   = bb ? vdwBf    : cheBf;
        const float* Wb    = bb ? vdwW     : cheW;
        const float* bfull = bb ? vdwBfull : cheBfull;
        float s = bfull[jc];
        for (int h2 = 0; h2 < 128; ++h2)
            s = fmaf(bfv[h2], Wb[(128 + h2) * 256 + jc], s);
        biasP[t] = LOG2E * s;
    }
}

// ---------- kernel 3: proj GEMM via MFMA — P[n][512] = bf16pack(nodes @ W) ----------
__global__ __launch_bounds__(256) void proj_mfma(const float* __restrict__ nodes,
                                                 const unsigned short* __restrict__ Pfrag,
                                                 unsigned int* __restrict__ P) {
    __shared__ unsigned short ln[16 * 136];
    int n0 = blockIdx.x * 16;
    int t = threadIdx.x;
    {
        int row = t >> 4, seg = t & 15;
        const float* src = &nodes[(n0 + row) * 128 + seg * 8];
        float4 v0 = *(const float4*)src;
        float4 v1 = *(const float4*)(src + 4);
        uint4 u;
        u.x = pack_bf2(v0.x, v0.y);
        u.y = pack_bf2(v0.z, v0.w);
        u.z = pack_bf2(v1.x, v1.y);
        u.w = pack_bf2(v1.z, v1.w);
        *(uint4*)&ln[row * 136 + seg * 8] = u;
    }
    __syncthreads();

    int w = t >> 6, l = t & 63, lhi = l >> 4, llo = l & 15;
    bf16x8 Af[4];
#pragma unroll
    for (int ks = 0; ks < 4; ++ks)
        Af[ks] = *(const bf16x8*)&ln[llo * 136 + ks * 32 + lhi * 8];

#pragma unroll
    for (int tp = 0; tp < 8; ++tp) {
        int ft = w * 8 + tp;        // filt tile
        int ct = 32 + w * 8 + tp;   // core tile
        f32x4 cf = {0.f, 0.f, 0.f, 0.f};
        f32x4 cc = {0.f, 0.f, 0.f, 0.f};
#pragma unroll
        for (int ks = 0; ks < 4; ++ks) {
            bf16x8 Bf = *(const bf16x8*)&Pfrag[((ft * 4 + ks) * 64 + l) * 8];
            bf16x8 Bc = *(const bf16x8*)&Pfrag[((ct * 4 + ks) * 64 + l) * 8];
            cf = __builtin_amdgcn_mfma_f32_16x16x32_bf16(Af[ks], Bf, cf, 0, 0, 0);
            cc = __builtin_amdgcn_mfma_f32_16x16x32_bf16(Af[ks], Bc, cc, 0, 0, 0);
        }
        int j = w * 128 + tp * 16 + llo;
#pragma unroll
        for (int r = 0; r < 4; ++r)
            P[(size_t)(n0 + lhi * 4 + r) * 512 + j] = pack_bf2(cf[r], cc[r]);
    }
}

// ---------- kernel 4: main — persistent blocks, cross-node double buffer ----------
// grid = 2048 (8 blocks/CU, one residency generation); block strides nodes by GRID.
// Per node: issue next node's loads -> compute current -> LDS-write staged regs -> barrier.
__global__ __launch_bounds__(256) void main_kernel(
    const float* __restrict__ nodes,
    const float* __restrict__ rbf_che, const int* __restrict__ idx_che,
    const float* __restrict__ rbf_vdw, const int* __restrict__ idx_vdw,
    const unsigned int* __restrict__ P,
    const unsigned short* __restrict__ Bfrag, const float* __restrict__ biasP,
    float* __restrict__ out) {
    __shared__ unsigned short sA[2][2 * 32 * 40];   // 10240 B (double buffer)
    __shared__ int sidx[2][64];                     // 512 B
    int bid = blockIdx.x;
    int tid = threadIdx.x;
    int w = tid >> 6, l = tid & 63;
    int lhi = l >> 4, llo = l & 15;
    int wold = w >> 1, whalf = w & 1;

    // one-time zero pad (k=20..31) for BOTH buffers
    if (tid < 192) {
        int row = tid / 3, j = tid - row * 3;
        *(uint2*)&sA[0][row * 40 + 20 + j * 4] = make_uint2(0u, 0u);
        *(uint2*)&sA[1][row * 40 + 20 + j * 4] = make_uint2(0u, 0u);
    }

    // per-thread staging decomposition (node-invariant)
    int i0 = tid;                               // < 320
    int b0 = i0 >= 160 ? 1 : 0, rem0 = i0 - b0 * 160;
    int m0 = rem0 / 5, kq0 = rem0 - m0 * 5;
    int i1 = 256 + tid;                         // only tid<64: in [256,320), b=1
    int m1 = (i1 - 160) / 5, kq1 = (i1 - 160) - m1 * 5;
    bool do1 = tid < 64;
    const float* src0 = b0 ? rbf_vdw : rbf_che;

    // prefetch + stage node `bid` into buf 0
    float4 v0, v1;
    int myidx = 0;
    {
        v0 = *(const float4*)&src0[bid * 640 + m0 * 20 + kq0 * 4];
        if (do1) {
            v1 = *(const float4*)&rbf_vdw[bid * 640 + m1 * 20 + kq1 * 4];
            myidx = (tid >= 32 ? idx_vdw : idx_che)[bid * MM + (tid & 31)];
        }
        uint2 p;
        p.x = pack_bf2(v0.x, v0.y);
        p.y = pack_bf2(v0.z, v0.w);
        *(uint2*)&sA[0][(b0 * 32 + m0) * 40 + kq0 * 4] = p;
        if (do1) {
            uint2 q;
            q.x = pack_bf2(v1.x, v1.y);
            q.y = pack_bf2(v1.z, v1.w);
            *(uint2*)&sA[0][(32 + m1) * 40 + kq1 * 4] = q;
            sidx[0][tid] = myidx;
        }
    }
    __syncthreads();

    int cur = 0;
    for (int n = bid; n < NN; n += GRID) {
        int nn = n + GRID;
        bool havenext = nn < NN;
        // issue next node's global loads early (consumed only after compute)
        if (havenext) {
            v0 = *(const float4*)&src0[nn * 640 + m0 * 20 + kq0 * 4];
            if (do1) {
                v1 = *(const float4*)&rbf_vdw[nn * 640 + m1 * 20 + kq1 * 4];
                myidx = (tid >= 32 ? idx_vdw : idx_che)[nn * MM + (tid & 31)];
            }
        }

        // ---- compute on buf `cur` ----
        const unsigned short* sAc = sA[cur];
        const int* sic = sidx[cur];
        float ps0 = 0.f, ps1 = 0.f;

#pragma unroll
        for (int b = 0; b < 2; ++b) {
            bf16x8 Af0 = *(const bf16x8*)&sAc[(b * 32 + llo) * 40 + lhi * 8];
            bf16x8 Af1 = *(const bf16x8*)&sAc[(b * 32 + 16 + llo) * 40 + lhi * 8];
            int4 vi0 = *(const int4*)&sic[b * 32 + lhi * 4];
            int4 vi1 = *(const int4*)&sic[b * 32 + 16 + lhi * 4];

            int secofs = b * 256 + 128 + w * 32 + llo;
            const unsigned int* gp[8];
            gp[0] = P + (size_t)vi0.x * 512 + secofs;
            gp[1] = P + (size_t)vi0.y * 512 + secofs;
            gp[2] = P + (size_t)vi0.z * 512 + secofs;
            gp[3] = P + (size_t)vi0.w * 512 + secofs;
            gp[4] = P + (size_t)vi1.x * 512 + secofs;
            gp[5] = P + (size_t)vi1.y * 512 + secofs;
            gp[6] = P + (size_t)vi1.z * 512 + secofs;
            gp[7] = P + (size_t)vi1.w * 512 + secofs;

            const unsigned int* sp = P + (size_t)n * 512 + b * 256 + w * 32 + llo;
            const float* bfp = biasP + b * 256 + w * 32 + llo;
            const unsigned short* bb = Bfrag + (size_t)((b * 2 + wold) * 8 + whalf * 4) * 512;

#pragma unroll
            for (int ht = 0; ht < 2; ++ht) {
                bf16x8 Bff = *(const bf16x8*)(bb + ((ht * 2) * 64 + l) * 8);
                bf16x8 Bfc = *(const bf16x8*)(bb + ((ht * 2 + 1) * 64 + l) * 8);

                unsigned int su = sp[ht * 16];
                float baseF = bfp[ht * 16]       + bf_lo(su);
                float baseC = bfp[ht * 16 + 128] + bf_hi(su);

                f32x4 a0f = {baseF, baseF, baseF, baseF};
                f32x4 a0c = {baseC, baseC, baseC, baseC};
                f32x4 a1f = a0f, a1c = a0c;
                a0f = __builtin_amdgcn_mfma_f32_16x16x32_bf16(Af0, Bff, a0f, 0, 0, 0);
                a0c = __builtin_amdgcn_mfma_f32_16x16x32_bf16(Af0, Bfc, a0c, 0, 0, 0);
                a1f = __builtin_amdgcn_mfma_f32_16x16x32_bf16(Af1, Bff, a1f, 0, 0, 0);
                a1c = __builtin_amdgcn_mfma_f32_16x16x32_bf16(Af1, Bfc, a1c, 0, 0, 0);

                float s = 0.f;
                // log2e-scaled: sigmoid = rcp(1+2^-f); softplus/ln2 = log2(1+2^c)
#pragma unroll
                for (int r = 0; r < 4; ++r) {
                    unsigned int g = gp[r][ht * 16];
                    float filt = a0f[r] + bf_lo(g);
                    float core = a0c[r] + bf_hi(g);
                    float sg = __builtin_amdgcn_rcpf(1.f + __builtin_amdgcn_exp2f(-filt));
                    float sop = __builtin_amdgcn_logf(1.f + __builtin_amdgcn_exp2f(core));
                    s = fmaf(sg, sop, s);
                }
#pragma unroll
                for (int r = 0; r < 4; ++r) {
                    unsigned int g = gp[4 + r][ht * 16];
                    float filt = a1f[r] + bf_lo(g);
                    float core = a1c[r] + bf_hi(g);
                    float sg = __builtin_amdgcn_rcpf(1.f + __builtin_amdgcn_exp2f(-filt));
                    float sop = __builtin_amdgcn_logf(1.f + __builtin_amdgcn_exp2f(core));
                    s = fmaf(sg, sop, s);
                }
                if (ht == 0) ps0 += s;
                else ps1 += s;
            }
        }

        float r0 = ps0;
        r0 += __shfl_xor(r0, 16);
        r0 += __shfl_xor(r0, 32);
        float r1 = ps1;
        r1 += __shfl_xor(r1, 16);
        r1 += __shfl_xor(r1, 32);

        if (lhi < 2) {
            int h = w * 32 + lhi * 16 + llo;
            float res = lhi ? r1 : r0;
            float x = nodes[n * 128 + h] + LN2 * res;
            out[n * 128 + h] = softplusf(x);
        }

        // ---- write staged regs into the other buffer ----
        if (havenext) {
            int nxt = cur ^ 1;
            uint2 p;
            p.x = pack_bf2(v0.x, v0.y);
            p.y = pack_bf2(v0.z, v0.w);
            *(uint2*)&sA[nxt][(b0 * 32 + m0) * 40 + kq0 * 4] = p;
            if (do1) {
                uint2 q;
                q.x = pack_bf2(v1.x, v1.y);
                q.y = pack_bf2(v1.z, v1.w);
                *(uint2*)&sA[nxt][(32 + m1) * 40 + kq1 * 4] = q;
                sidx[nxt][tid] = myidx;
            }
        }
        __syncthreads();
        cur ^= 1;
    }
}

// ---------- launch ----------
extern "C" void kernel_launch(void* const* d_in, const int* in_sizes, int n_in,
                              void* d_out, int out_size, void* d_ws, size_t ws_size,
                              hipStream_t stream) {
    const float* nodes     = (const float*)d_in[0];
    const float* che_rbf   = (const float*)d_in[1];
    const int*   che_idx   = (const int*)d_in[2];
    const float* vdw_rbf   = (const float*)d_in[3];
    const int*   vdw_idx   = (const int*)d_in[4];
    const float* che_Wf    = (const float*)d_in[5];
    const float* che_bf    = (const float*)d_in[6];
    const float* che_Wfull = (const float*)d_in[7];
    const float* che_bfull = (const float*)d_in[8];
    const float* vdw_Wf    = (const float*)d_in[9];
    const float* vdw_bf    = (const float*)d_in[10];
    const float* vdw_Wfull = (const float*)d_in[11];
    const float* vdw_bfull = (const float*)d_in[12];

    char* ws = (char*)d_ws;
    unsigned short* Pfrag = (unsigned short*)ws;              // 256 KB
    unsigned short* Bfrag = (unsigned short*)(ws + 262144);   // 32 KB
    float* biasP          = (float*)(ws + 294912);            // 2 KB
    unsigned int* P       = (unsigned int*)(ws + 299008);     // 40.96 MB

    build_pfrag<<<512, 256, 0, stream>>>(che_Wfull, vdw_Wfull, Pfrag);
    build_bfrag<<<8, 256, 0, stream>>>(che_Wf, che_bf, che_Wfull, che_bfull,
                                       vdw_Wf, vdw_bf, vdw_Wfull, vdw_bfull,
                                       Bfrag, biasP);
    proj_mfma<<<NN / 16, 256, 0, stream>>>(nodes, Pfrag, P);
    main_kernel<<<GRID, 256, 0, stream>>>(nodes, che_rbf, che_idx, vdw_rbf, vdw_idx,
                                          P, Bfrag, biasP, (float*)d_out);
}

// Round 12
// 170.362 us; speedup vs baseline: 1.7039x; 1.7039x over previous
//
#include <hip/hip_runtime.h>
#include <hip/hip_bf16.h>

#define NN 20000
#define MM 32
#define EE 20
#define HH 128
#define LOG2E 1.44269504088896f
#define LN2   0.69314718055995f

typedef __attribute__((ext_vector_type(8))) short bf16x8;
typedef __attribute__((ext_vector_type(4))) float f32x4;

// ---------- helpers ----------
__device__ __forceinline__ float bf_lo(unsigned int u) {
    return __uint_as_float(u << 16);
}
__device__ __forceinline__ float bf_hi(unsigned int u) {
    return __uint_as_float(u & 0xFFFF0000u);
}
__device__ __forceinline__ unsigned int pack_bf2(float lo, float hi) {
    unsigned int a = __float_as_uint(lo);
    unsigned int b = __float_as_uint(hi);
    a += 0x7FFFu + ((a >> 16) & 1u);
    b += 0x7FFFu + ((b >> 16) & 1u);
    return (a >> 16) | (b & 0xFFFF0000u);
}
__device__ __forceinline__ unsigned short bf16r(float v) {
    unsigned int u = __float_as_uint(v);
    u += 0x7FFFu + ((u >> 16) & 1u);
    return (unsigned short)(u >> 16);
}
__device__ __forceinline__ float softplusf(float x) {
    return fmaxf(x, 0.f) + __logf(1.f + __expf(-fabsf(x)));
}

// ---------- kernel 1: build Pfrag — MFMA B fragments of proj weights (bf16) ----------
// Pre-scaled by LOG2E.
__global__ void build_pfrag(const float* __restrict__ cheW,
                            const float* __restrict__ vdwW,
                            unsigned short* __restrict__ Pfrag) {
    int t = blockIdx.x * 256 + threadIdx.x;   // < 131072
    int i = t & 7;
    int l = (t >> 3) & 63;
    int ks = (t >> 9) & 3;
    int tile = t >> 11;                       // 0..63
    int j = (tile & 31) * 16 + (l & 15);      // pair col < 512
    int slot = tile >> 5;
    int b = j >> 8, sec = (j >> 7) & 1, h = j & 127;
    int klocal = (l >> 4) * 8 + i;
    int row = (sec ? 256 : 0) + ks * 32 + klocal;
    const float* W = b ? vdwW : cheW;
    Pfrag[t] = bf16r(LOG2E * W[row * 256 + slot * 128 + h]);
}

// ---------- kernel 2: build Bfrag (edge-weight MFMA B fragments) + biasP ----------
// Both pre-scaled by LOG2E.
__global__ void build_bfrag(const float* __restrict__ cheWf, const float* __restrict__ cheBf,
                            const float* __restrict__ cheW,  const float* __restrict__ cheBfull,
                            const float* __restrict__ vdwWf, const float* __restrict__ vdwBf,
                            const float* __restrict__ vdwW,  const float* __restrict__ vdwBfull,
                            unsigned short* __restrict__ Bfrag, float* __restrict__ biasP) {
    int t = blockIdx.x * 256 + threadIdx.x;   // < 2048
    int b = t >> 10, w = (t >> 9) & 1, tc = (t >> 6) & 7, l = t & 63;
    int lhi = l >> 4, llo = l & 15;
    int h = w * 64 + (tc >> 1) * 16 + llo;    // < 128
    int slot = tc & 1;
    int jcol = slot * 128 + h;                // < 256
    const float* Wf = b ? vdwWf : cheWf;
    const float* W  = b ? vdwW  : cheW;

    unsigned short o[8];
#pragma unroll
    for (int i = 0; i < 8; ++i) {
        int k = lhi * 8 + i;
        float a = 0.f;
        if (k < EE)
            for (int h2 = 0; h2 < 128; ++h2)
                a = fmaf(Wf[k * 128 + h2], W[(128 + h2) * 256 + jcol], a);
        o[i] = bf16r(LOG2E * a);
    }
#pragma unroll
    for (int i = 0; i < 8; ++i) Bfrag[t * 8 + i] = o[i];

    if (t < 512) {
        int bb = t >> 8, sl = (t >> 7) & 1, hh = t & 127;
        int jc = sl * 128 + hh;
        const float* bfv   = bb ? vdwBf    : cheBf;
        const float* Wb    = bb ? vdwW     : cheW;
        const float* bfull = bb ? vdwBfull : cheBfull;
        float s = bfull[jc];
        for (int h2 = 0; h2 < 128; ++h2)
            s = fmaf(bfv[h2], Wb[(128 + h2) * 256 + jc], s);
        biasP[t] = LOG2E * s;
    }
}

// ---------- kernel 3: proj GEMM via MFMA — P[n][512]; bias folded into SELF cols ----------
__global__ __launch_bounds__(256) void proj_mfma(const float* __restrict__ nodes,
                                                 const unsigned short* __restrict__ Pfrag,
                                                 const float* __restrict__ biasP,
                                                 unsigned int* __restrict__ P) {
    __shared__ unsigned short ln[16 * 136];
    int n0 = blockIdx.x * 16;
    int t = threadIdx.x;
    {
        int row = t >> 4, seg = t & 15;
        const float* src = &nodes[(n0 + row) * 128 + seg * 8];
        float4 v0 = *(const float4*)src;
        float4 v1 = *(const float4*)(src + 4);
        uint4 u;
        u.x = pack_bf2(v0.x, v0.y);
        u.y = pack_bf2(v0.z, v0.w);
        u.z = pack_bf2(v1.x, v1.y);
        u.w = pack_bf2(v1.z, v1.w);
        *(uint4*)&ln[row * 136 + seg * 8] = u;
    }
    __syncthreads();

    int w = t >> 6, l = t & 63, lhi = l >> 4, llo = l & 15;
    bf16x8 Af[4];
#pragma unroll
    for (int ks = 0; ks < 4; ++ks)
        Af[ks] = *(const bf16x8*)&ln[llo * 136 + ks * 32 + lhi * 8];

#pragma unroll
    for (int tp = 0; tp < 8; ++tp) {
        int ft = w * 8 + tp;        // filt tile
        int ct = 32 + w * 8 + tp;   // core tile
        f32x4 cf = {0.f, 0.f, 0.f, 0.f};
        f32x4 cc = {0.f, 0.f, 0.f, 0.f};
#pragma unroll
        for (int ks = 0; ks < 4; ++ks) {
            bf16x8 Bf = *(const bf16x8*)&Pfrag[((ft * 4 + ks) * 64 + l) * 8];
            bf16x8 Bc = *(const bf16x8*)&Pfrag[((ct * 4 + ks) * 64 + l) * 8];
            cf = __builtin_amdgcn_mfma_f32_16x16x32_bf16(Af[ks], Bf, cf, 0, 0, 0);
            cc = __builtin_amdgcn_mfma_f32_16x16x32_bf16(Af[ks], Bc, cc, 0, 0, 0);
        }
        int j = w * 128 + tp * 16 + llo;   // pair col
        // fold bias into the SELF section only (sec bit == 0); nbr cols unchanged
        float bF2 = 0.f, bC2 = 0.f;
        if ((j & 128) == 0) {
            int bb = j >> 8, hh = j & 127;
            bF2 = biasP[bb * 256 + hh];
            bC2 = biasP[bb * 256 + 128 + hh];
        }
#pragma unroll
        for (int r = 0; r < 4; ++r)
            P[(size_t)(n0 + lhi * 4 + r) * 512 + j] = pack_bf2(cf[r] + bF2, cc[r] + bC2);
    }
}

// ---------- kernel 4: main — R10 structure + leaner pair body ----------
// one block per node, 256 threads = 4 waves; wave w owns h in [w*32, w*32+32)
// R11 lesson: keep blocks short and uncoupled — no persistent loop, no per-node barriers.
__global__ __launch_bounds__(256) void main_kernel(
    const float* __restrict__ nodes,
    const float* __restrict__ rbf_che, const int* __restrict__ idx_che,
    const float* __restrict__ rbf_vdw, const int* __restrict__ idx_vdw,
    const unsigned int* __restrict__ P,
    const unsigned short* __restrict__ Bfrag,
    float* __restrict__ out) {
    __shared__ unsigned short sA[2 * 32 * 40];
    __shared__ int sidx[2][MM];
    int n = blockIdx.x;
    int tid = threadIdx.x;
    int w = tid >> 6, l = tid & 63;       // w in {0..3}
    int lhi = l >> 4, llo = l & 15;
    int wold = w >> 1, whalf = w & 1;

    if (tid < 192) {
        int row = tid / 3, j = tid - row * 3;
        *(uint2*)&sA[row * 40 + 20 + j * 4] = make_uint2(0u, 0u);
    }
    for (int i = tid; i < 320; i += 256) {
        int b = (i >= 160) ? 1 : 0, rem = i - b * 160;
        int m = rem / 5, kq = rem - m * 5;
        const float* src = b ? rbf_vdw : rbf_che;
        float4 v = *(const float4*)&src[n * 640 + m * 20 + kq * 4];
        uint2 p;
        p.x = pack_bf2(v.x, v.y);
        p.y = pack_bf2(v.z, v.w);
        *(uint2*)&sA[(b * 32 + m) * 40 + kq * 4] = p;
    }
    if (tid < 64) {
        int b = tid >> 5, m = tid & 31;
        sidx[b][m] = (b ? idx_vdw : idx_che)[n * MM + m];
    }
    __syncthreads();

    float ps0 = 0.f, ps1 = 0.f;

#pragma unroll
    for (int b = 0; b < 2; ++b) {
        bf16x8 Af0 = *(const bf16x8*)&sA[(b * 32 + llo) * 40 + lhi * 8];
        bf16x8 Af1 = *(const bf16x8*)&sA[(b * 32 + 16 + llo) * 40 + lhi * 8];
        int4 vi0 = *(const int4*)&sidx[b][lhi * 4];
        int4 vi1 = *(const int4*)&sidx[b][16 + lhi * 4];

        int secofs = b * 256 + 128 + w * 32 + llo;
        const unsigned int* gp[8];
        gp[0] = P + (size_t)vi0.x * 512 + secofs;
        gp[1] = P + (size_t)vi0.y * 512 + secofs;
        gp[2] = P + (size_t)vi0.z * 512 + secofs;
        gp[3] = P + (size_t)vi0.w * 512 + secofs;
        gp[4] = P + (size_t)vi1.x * 512 + secofs;
        gp[5] = P + (size_t)vi1.y * 512 + secofs;
        gp[6] = P + (size_t)vi1.z * 512 + secofs;
        gp[7] = P + (size_t)vi1.w * 512 + secofs;

        const unsigned int* sp = P + (size_t)n * 512 + b * 256 + w * 32 + llo;
        const unsigned short* bb = Bfrag + (size_t)((b * 2 + wold) * 8 + whalf * 4) * 512;

#pragma unroll
        for (int ht = 0; ht < 2; ++ht) {
            bf16x8 Bff = *(const bf16x8*)(bb + ((ht * 2) * 64 + l) * 8);
            bf16x8 Bfc = *(const bf16x8*)(bb + ((ht * 2 + 1) * 64 + l) * 8);

            unsigned int su = sp[ht * 16];      // bias already folded in
            float baseF = bf_lo(su);
            float baseC = bf_hi(su);

            f32x4 a0f = {baseF, baseF, baseF, baseF};
            f32x4 a0c = {baseC, baseC, baseC, baseC};
            f32x4 a1f = a0f, a1c = a0c;
            a0f = __builtin_amdgcn_mfma_f32_16x16x32_bf16(Af0, Bff, a0f, 0, 0, 0);
            a0c = __builtin_amdgcn_mfma_f32_16x16x32_bf16(Af0, Bfc, a0c, 0, 0, 0);
            a1f = __builtin_amdgcn_mfma_f32_16x16x32_bf16(Af1, Bff, a1f, 0, 0, 0);
            a1c = __builtin_amdgcn_mfma_f32_16x16x32_bf16(Af1, Bfc, a1c, 0, 0, 0);

            float s = 0.f;
            // log2e-scaled: sigmoid = rcp(1+2^-f); softplus/ln2 = log2(1+2^c)
            // core-unpack unmasked: low-16 garbage mantissa <= 2^-17 rel err
#pragma unroll
            for (int r = 0; r < 4; ++r) {
                unsigned int g = gp[r][ht * 16];
                float filt = a0f[r] + bf_lo(g);
                float core = a0c[r] + __uint_as_float(g);
                float sg = __builtin_amdgcn_rcpf(1.f + __builtin_amdgcn_exp2f(-filt));
                float sop = __builtin_amdgcn_logf(1.f + __builtin_amdgcn_exp2f(core));
                s = fmaf(sg, sop, s);
            }
#pragma unroll
            for (int r = 0; r < 4; ++r) {
                unsigned int g = gp[4 + r][ht * 16];
                float filt = a1f[r] + bf_lo(g);
                float core = a1c[r] + __uint_as_float(g);
                float sg = __builtin_amdgcn_rcpf(1.f + __builtin_amdgcn_exp2f(-filt));
                float sop = __builtin_amdgcn_logf(1.f + __builtin_amdgcn_exp2f(core));
                s = fmaf(sg, sop, s);
            }
            if (ht == 0) ps0 += s;
            else ps1 += s;
        }
    }

    float v0 = ps0;
    v0 += __shfl_xor(v0, 16);
    v0 += __shfl_xor(v0, 32);
    float v1 = ps1;
    v1 += __shfl_xor(v1, 16);
    v1 += __shfl_xor(v1, 32);

    if (lhi < 2) {
        int h = w * 32 + lhi * 16 + llo;   // < 128
        float res = lhi ? v1 : v0;
        float x = nodes[n * 128 + h] + LN2 * res;
        out[n * 128 + h] = softplusf(x);
    }
}

// ---------- launch ----------
extern "C" void kernel_launch(void* const* d_in, const int* in_sizes, int n_in,
                              void* d_out, int out_size, void* d_ws, size_t ws_size,
                              hipStream_t stream) {
    const float* nodes     = (const float*)d_in[0];
    const float* che_rbf   = (const float*)d_in[1];
    const int*   che_idx   = (const int*)d_in[2];
    const float* vdw_rbf   = (const float*)d_in[3];
    const int*   vdw_idx   = (const int*)d_in[4];
    const float* che_Wf    = (const float*)d_in[5];
    const float* che_bf    = (const float*)d_in[6];
    const float* che_Wfull = (const float*)d_in[7];
    const float* che_bfull = (const float*)d_in[8];
    const float* vdw_Wf    = (const float*)d_in[9];
    const float* vdw_bf    = (const float*)d_in[10];
    const float* vdw_Wfull = (const float*)d_in[11];
    const float* vdw_bfull = (const float*)d_in[12];

    char* ws = (char*)d_ws;
    unsigned short* Pfrag = (unsigned short*)ws;              // 256 KB
    unsigned short* Bfrag = (unsigned short*)(ws + 262144);   // 32 KB
    float* biasP          = (float*)(ws + 294912);            // 2 KB
    unsigned int* P       = (unsigned int*)(ws + 299008);     // 40.96 MB

    build_pfrag<<<512, 256, 0, stream>>>(che_Wfull, vdw_Wfull, Pfrag);
    build_bfrag<<<8, 256, 0, stream>>>(che_Wf, che_bf, che_Wfull, che_bfull,
                                       vdw_Wf, vdw_bf, vdw_Wfull, vdw_bfull,
                                       Bfrag, biasP);
    proj_mfma<<<NN / 16, 256, 0, stream>>>(nodes, Pfrag, biasP, P);
    main_kernel<<<NN, 256, 0, stream>>>(nodes, che_rbf, che_idx, vdw_rbf, vdw_idx,
                                        P, Bfrag, (float*)d_out);
}

// Round 13
// 167.177 us; speedup vs baseline: 1.7364x; 1.0191x over previous
//
#include <hip/hip_runtime.h>
#include <hip/hip_bf16.h>

#define NN 20000
#define MM 32
#define EE 20
#define HH 128
#define LOG2E 1.44269504088896f
#define LN2   0.69314718055995f

typedef __attribute__((ext_vector_type(8))) short bf16x8;
typedef __attribute__((ext_vector_type(4))) float f32x4;

// ---------- helpers ----------
__device__ __forceinline__ float bf_lo(unsigned int u) {
    return __uint_as_float(u << 16);
}
__device__ __forceinline__ float bf_hi(unsigned int u) {
    return __uint_as_float(u & 0xFFFF0000u);
}
__device__ __forceinline__ unsigned int pack_bf2(float lo, float hi) {
    unsigned int a = __float_as_uint(lo);
    unsigned int b = __float_as_uint(hi);
    a += 0x7FFFu + ((a >> 16) & 1u);
    b += 0x7FFFu + ((b >> 16) & 1u);
    return (a >> 16) | (b & 0xFFFF0000u);
}
__device__ __forceinline__ unsigned short bf16r(float v) {
    unsigned int u = __float_as_uint(v);
    u += 0x7FFFu + ((u >> 16) & 1u);
    return (unsigned short)(u >> 16);
}
__device__ __forceinline__ float softplusf(float x) {
    return fmaxf(x, 0.f) + __logf(1.f + __expf(-fabsf(x)));
}

// ---------- kernel 1: build Pfrag — MFMA B fragments of proj weights (bf16) ----------
// Pre-scaled by LOG2E.
__global__ void build_pfrag(const float* __restrict__ cheW,
                            const float* __restrict__ vdwW,
                            unsigned short* __restrict__ Pfrag) {
    int t = blockIdx.x * 256 + threadIdx.x;   // < 131072
    int i = t & 7;
    int l = (t >> 3) & 63;
    int ks = (t >> 9) & 3;
    int tile = t >> 11;                       // 0..63
    int j = (tile & 31) * 16 + (l & 15);      // pair col < 512
    int slot = tile >> 5;
    int b = j >> 8, sec = (j >> 7) & 1, h = j & 127;
    int klocal = (l >> 4) * 8 + i;
    int row = (sec ? 256 : 0) + ks * 32 + klocal;
    const float* W = b ? vdwW : cheW;
    Pfrag[t] = bf16r(LOG2E * W[row * 256 + slot * 128 + h]);
}

// ---------- kernel 2: build Bfrag (edge-weight MFMA B fragments) + biasP ----------
// Both pre-scaled by LOG2E.
__global__ void build_bfrag(const float* __restrict__ cheWf, const float* __restrict__ cheBf,
                            const float* __restrict__ cheW,  const float* __restrict__ cheBfull,
                            const float* __restrict__ vdwWf, const float* __restrict__ vdwBf,
                            const float* __restrict__ vdwW,  const float* __restrict__ vdwBfull,
                            unsigned short* __restrict__ Bfrag, float* __restrict__ biasP) {
    int t = blockIdx.x * 256 + threadIdx.x;   // < 2048
    int b = t >> 10, w = (t >> 9) & 1, tc = (t >> 6) & 7, l = t & 63;
    int lhi = l >> 4, llo = l & 15;
    int h = w * 64 + (tc >> 1) * 16 + llo;    // < 128
    int slot = tc & 1;
    int jcol = slot * 128 + h;                // < 256
    const float* Wf = b ? vdwWf : cheWf;
    const float* W  = b ? vdwW  : cheW;

    unsigned short o[8];
#pragma unroll
    for (int i = 0; i < 8; ++i) {
        int k = lhi * 8 + i;
        float a = 0.f;
        if (k < EE)
            for (int h2 = 0; h2 < 128; ++h2)
                a = fmaf(Wf[k * 128 + h2], W[(128 + h2) * 256 + jcol], a);
        o[i] = bf16r(LOG2E * a);
    }
#pragma unroll
    for (int i = 0; i < 8; ++i) Bfrag[t * 8 + i] = o[i];

    if (t < 512) {
        int bb = t >> 8, sl = (t >> 7) & 1, hh = t & 127;
        int jc = sl * 128 + hh;
        const float* bfv   = bb ? vdwBf    : cheBf;
        const float* Wb    = bb ? vdwW     : cheW;
        const float* bfull = bb ? vdwBfull : cheBfull;
        float s = bfull[jc];
        for (int h2 = 0; h2 < 128; ++h2)
            s = fmaf(bfv[h2], Wb[(128 + h2) * 256 + jc], s);
        biasP[t] = LOG2E * s;
    }
}

// ---------- kernel 3: proj GEMM via MFMA — P[n][512]; bias folded into SELF cols ----------
__global__ __launch_bounds__(256) void proj_mfma(const float* __restrict__ nodes,
                                                 const unsigned short* __restrict__ Pfrag,
                                                 const float* __restrict__ biasP,
                                                 unsigned int* __restrict__ P) {
    __shared__ unsigned short ln[16 * 136];
    int n0 = blockIdx.x * 16;
    int t = threadIdx.x;
    {
        int row = t >> 4, seg = t & 15;
        const float* src = &nodes[(n0 + row) * 128 + seg * 8];
        float4 v0 = *(const float4*)src;
        float4 v1 = *(const float4*)(src + 4);
        uint4 u;
        u.x = pack_bf2(v0.x, v0.y);
        u.y = pack_bf2(v0.z, v0.w);
        u.z = pack_bf2(v1.x, v1.y);
        u.w = pack_bf2(v1.z, v1.w);
        *(uint4*)&ln[row * 136 + seg * 8] = u;
    }
    __syncthreads();

    int w = t >> 6, l = t & 63, lhi = l >> 4, llo = l & 15;
    bf16x8 Af[4];
#pragma unroll
    for (int ks = 0; ks < 4; ++ks)
        Af[ks] = *(const bf16x8*)&ln[llo * 136 + ks * 32 + lhi * 8];

#pragma unroll
    for (int tp = 0; tp < 8; ++tp) {
        int ft = w * 8 + tp;        // filt tile
        int ct = 32 + w * 8 + tp;   // core tile
        f32x4 cf = {0.f, 0.f, 0.f, 0.f};
        f32x4 cc = {0.f, 0.f, 0.f, 0.f};
#pragma unroll
        for (int ks = 0; ks < 4; ++ks) {
            bf16x8 Bf = *(const bf16x8*)&Pfrag[((ft * 4 + ks) * 64 + l) * 8];
            bf16x8 Bc = *(const bf16x8*)&Pfrag[((ct * 4 + ks) * 64 + l) * 8];
            cf = __builtin_amdgcn_mfma_f32_16x16x32_bf16(Af[ks], Bf, cf, 0, 0, 0);
            cc = __builtin_amdgcn_mfma_f32_16x16x32_bf16(Af[ks], Bc, cc, 0, 0, 0);
        }
        int j = w * 128 + tp * 16 + llo;   // pair col
        // fold bias into the SELF section only (sec bit == 0); nbr cols unchanged
        float bF2 = 0.f, bC2 = 0.f;
        if ((j & 128) == 0) {
            int bb = j >> 8, hh = j & 127;
            bF2 = biasP[bb * 256 + hh];
            bC2 = biasP[bb * 256 + 128 + hh];
        }
#pragma unroll
        for (int r = 0; r < 4; ++r)
            P[(size_t)(n0 + lhi * 4 + r) * 512 + j] = pack_bf2(cf[r] + bF2, cc[r] + bC2);
    }
}

// ---------- kernel 4: main — R12 structure, trans ops replaced by LDS tables ----------
// one block per node, 256 threads = 4 waves; wave w owns h in [w*32, w*32+32)
// stab[512]: sigmoid over filt' in [-8,8] step 1/32 (log2e-scaled domain)
// rtab[256]: r(t)=log2(1+2^-t) over [0,8]; softplus' = max(c,0)+r(|c|)
__global__ __launch_bounds__(256) void main_kernel(
    const float* __restrict__ nodes,
    const float* __restrict__ rbf_che, const int* __restrict__ idx_che,
    const float* __restrict__ rbf_vdw, const int* __restrict__ idx_vdw,
    const unsigned int* __restrict__ P,
    const unsigned short* __restrict__ Bfrag,
    float* __restrict__ out) {
    __shared__ unsigned short sA[2 * 32 * 40];
    __shared__ int sidx[2][MM];
    __shared__ float stab[512];
    __shared__ float rtab[256];
    int n = blockIdx.x;
    int tid = threadIdx.x;
    int w = tid >> 6, l = tid & 63;       // w in {0..3}
    int lhi = l >> 4, llo = l & 15;
    int wold = w >> 1, whalf = w & 1;

    // build gate tables (768 trans total, amortized over 8192 pairs)
    for (int i = tid; i < 768; i += 256) {
        if (i < 512) {
            float f = (float)(i - 256) * 0.03125f;
            stab[i] = 1.f / (1.f + __builtin_amdgcn_exp2f(-f));
        } else {
            float t2 = (float)(i - 512) * 0.03125f;
            rtab[i - 512] = __builtin_amdgcn_logf(1.f + __builtin_amdgcn_exp2f(-t2));
        }
    }

    if (tid < 192) {
        int row = tid / 3, j = tid - row * 3;
        *(uint2*)&sA[row * 40 + 20 + j * 4] = make_uint2(0u, 0u);
    }
    for (int i = tid; i < 320; i += 256) {
        int b = (i >= 160) ? 1 : 0, rem = i - b * 160;
        int m = rem / 5, kq = rem - m * 5;
        const float* src = b ? rbf_vdw : rbf_che;
        float4 v = *(const float4*)&src[n * 640 + m * 20 + kq * 4];
        uint2 p;
        p.x = pack_bf2(v.x, v.y);
        p.y = pack_bf2(v.z, v.w);
        *(uint2*)&sA[(b * 32 + m) * 40 + kq * 4] = p;
    }
    if (tid < 64) {
        int b = tid >> 5, m = tid & 31;
        sidx[b][m] = (b ? idx_vdw : idx_che)[n * MM + m];
    }
    __syncthreads();

    float ps0 = 0.f, ps1 = 0.f;

#pragma unroll
    for (int b = 0; b < 2; ++b) {
        bf16x8 Af0 = *(const bf16x8*)&sA[(b * 32 + llo) * 40 + lhi * 8];
        bf16x8 Af1 = *(const bf16x8*)&sA[(b * 32 + 16 + llo) * 40 + lhi * 8];
        int4 vi0 = *(const int4*)&sidx[b][lhi * 4];
        int4 vi1 = *(const int4*)&sidx[b][16 + lhi * 4];

        int secofs = b * 256 + 128 + w * 32 + llo;
        const unsigned int* gp[8];
        gp[0] = P + (size_t)vi0.x * 512 + secofs;
        gp[1] = P + (size_t)vi0.y * 512 + secofs;
        gp[2] = P + (size_t)vi0.z * 512 + secofs;
        gp[3] = P + (size_t)vi0.w * 512 + secofs;
        gp[4] = P + (size_t)vi1.x * 512 + secofs;
        gp[5] = P + (size_t)vi1.y * 512 + secofs;
        gp[6] = P + (size_t)vi1.z * 512 + secofs;
        gp[7] = P + (size_t)vi1.w * 512 + secofs;

        const unsigned int* sp = P + (size_t)n * 512 + b * 256 + w * 32 + llo;
        const unsigned short* bb = Bfrag + (size_t)((b * 2 + wold) * 8 + whalf * 4) * 512;

#pragma unroll
        for (int ht = 0; ht < 2; ++ht) {
            bf16x8 Bff = *(const bf16x8*)(bb + ((ht * 2) * 64 + l) * 8);
            bf16x8 Bfc = *(const bf16x8*)(bb + ((ht * 2 + 1) * 64 + l) * 8);

            unsigned int su = sp[ht * 16];      // bias already folded in
            float baseF = bf_lo(su);
            float baseC = bf_hi(su);

            f32x4 a0f = {baseF, baseF, baseF, baseF};
            f32x4 a0c = {baseC, baseC, baseC, baseC};
            f32x4 a1f = a0f, a1c = a0c;
            a0f = __builtin_amdgcn_mfma_f32_16x16x32_bf16(Af0, Bff, a0f, 0, 0, 0);
            a0c = __builtin_amdgcn_mfma_f32_16x16x32_bf16(Af0, Bfc, a0c, 0, 0, 0);
            a1f = __builtin_amdgcn_mfma_f32_16x16x32_bf16(Af1, Bff, a1f, 0, 0, 0);
            a1c = __builtin_amdgcn_mfma_f32_16x16x32_bf16(Af1, Bfc, a1c, 0, 0, 0);

            float s = 0.f;
#pragma unroll
            for (int r = 0; r < 4; ++r) {
                unsigned int g = gp[r][ht * 16];
                float filt = a0f[r] + bf_lo(g);
                float core = a0c[r] + __uint_as_float(g);
                int fi = (int)fminf(fmaxf(fmaf(filt, 32.f, 256.5f), 0.f), 511.f);
                int ci = (int)fminf(fmaf(fabsf(core), 32.f, 0.5f), 255.f);
                float sop = fmaxf(core, 0.f) + rtab[ci];
                s = fmaf(stab[fi], sop, s);
            }
#pragma unroll
            for (int r = 0; r < 4; ++r) {
                unsigned int g = gp[4 + r][ht * 16];
                float filt = a1f[r] + bf_lo(g);
                float core = a1c[r] + __uint_as_float(g);
                int fi = (int)fminf(fmaxf(fmaf(filt, 32.f, 256.5f), 0.f), 511.f);
                int ci = (int)fminf(fmaf(fabsf(core), 32.f, 0.5f), 255.f);
                float sop = fmaxf(core, 0.f) + rtab[ci];
                s = fmaf(stab[fi], sop, s);
            }
            if (ht == 0) ps0 += s;
            else ps1 += s;
        }
    }

    float v0 = ps0;
    v0 += __shfl_xor(v0, 16);
    v0 += __shfl_xor(v0, 32);
    float v1 = ps1;
    v1 += __shfl_xor(v1, 16);
    v1 += __shfl_xor(v1, 32);

    if (lhi < 2) {
        int h = w * 32 + lhi * 16 + llo;   // < 128
        float res = lhi ? v1 : v0;
        float x = nodes[n * 128 + h] + LN2 * res;
        out[n * 128 + h] = softplusf(x);
    }
}

// ---------- launch ----------
extern "C" void kernel_launch(void* const* d_in, const int* in_sizes, int n_in,
                              void* d_out, int out_size, void* d_ws, size_t ws_size,
                              hipStream_t stream) {
    const float* nodes     = (const float*)d_in[0];
    const float* che_rbf   = (const float*)d_in[1];
    const int*   che_idx   = (const int*)d_in[2];
    const float* vdw_rbf   = (const float*)d_in[3];
    const int*   vdw_idx   = (const int*)d_in[4];
    const float* che_Wf    = (const float*)d_in[5];
    const float* che_bf    = (const float*)d_in[6];
    const float* che_Wfull = (const float*)d_in[7];
    const float* che_bfull = (const float*)d_in[8];
    const float* vdw_Wf    = (const float*)d_in[9];
    const float* vdw_bf    = (const float*)d_in[10];
    const float* vdw_Wfull = (const float*)d_in[11];
    const float* vdw_bfull = (const float*)d_in[12];

    char* ws = (char*)d_ws;
    unsigned short* Pfrag = (unsigned short*)ws;              // 256 KB
    unsigned short* Bfrag = (unsigned short*)(ws + 262144);   // 32 KB
    float* biasP          = (float*)(ws + 294912);            // 2 KB
    unsigned int* P       = (unsigned int*)(ws + 299008);     // 40.96 MB

    build_pfrag<<<512, 256, 0, stream>>>(che_Wfull, vdw_Wfull, Pfrag);
    build_bfrag<<<8, 256, 0, stream>>>(che_Wf, che_bf, che_Wfull, che_bfull,
                                       vdw_Wf, vdw_bf, vdw_Wfull, vdw_bfull,
                                       Bfrag, biasP);
    proj_mfma<<<NN / 16, 256, 0, stream>>>(nodes, Pfrag, biasP, P);
    main_kernel<<<NN, 256, 0, stream>>>(nodes, che_rbf, che_idx, vdw_rbf, vdw_idx,
                                        P, Bfrag, (float*)d_out);
}